// Round 6
// baseline (262.201 us; speedup 1.0000x reference)
//
#include <hip/hip_runtime.h>
#include <stdint.h>

typedef short v8s __attribute__((ext_vector_type(8)));
typedef float v4f __attribute__((ext_vector_type(4)));

#define MFMA(a, b, c) __builtin_amdgcn_mfma_f32_16x16x32_bf16((a), (b), (c), 0, 0, 0)

__device__ __forceinline__ short f2bf(float f) {
  union { float f; uint32_t u; } v; v.f = f;
  uint32_t r = v.u + 0x7fffu + ((v.u >> 16) & 1u);
  return (short)(r >> 16);
}

// pack two fp32 -> two bf16 (truncate) in one v_perm_b32
__device__ __forceinline__ uint32_t pack2(float a, float b) {
  union { float f; uint32_t u; } ua, ub; ua.f = a; ub.f = b;
  return __builtin_amdgcn_perm(ub.u, ua.u, 0x07060302u);
}

__device__ __forceinline__ void gload16(const void* g, void* l) {
  __builtin_amdgcn_global_load_lds((const __attribute__((address_space(1))) void*)g,
                                   (__attribute__((address_space(3))) void*)l,
                                   16, 0, 0);
}

// ---------------- prep: permute + convert weights to bf16 ----------------
__global__ __launch_bounds__(256) void prep_kernel(
    const float* __restrict__ qkvw, const float* __restrict__ qkvb,
    const float* __restrict__ projw,
    short* __restrict__ Wq, short* __restrict__ Wp, float* __restrict__ bias2) {
  int idx = blockIdx.x * 256 + threadIdx.x;
  if (idx < 1536 * 512) {
    int r = idx >> 9, c = idx & 511;
    int sec = r >> 9;            // 0=q, 1=k, 2=v
    int rr = r & 511;
    int nh = rr >> 6, cc = rr & 63;
    int o = nh * 192 + sec * 64 + cc;
    Wq[idx] = f2bf(qkvw[o * 512 + c]);
    if (c == 0) bias2[r] = qkvb[o];
  } else {
    int j = idx - 1536 * 512;
    if (j < 512 * 512) Wp[j] = f2bf(projw[j]);
  }
}

// ---------------- groupnorm: writes hT[n=b*1024+t][c] bf16 ----------------
__global__ __launch_bounds__(256) void groupnorm_kernel(
    const float* __restrict__ x, const float* __restrict__ gw,
    const float* __restrict__ gb, short* __restrict__ hT) {
  __shared__ float red[8];
  __shared__ short tile[16 * 1032];
  int b = blockIdx.x >> 5, g = blockIdx.x & 31;
  int tid = threadIdx.x;
  const float* xg = x + (b * 512 + g * 16) * 1024;
  float s = 0.f, ss = 0.f;
#pragma unroll
  for (int r = 0; r < 16; ++r) {
    float4 v = *(const float4*)(xg + r * 1024 + tid * 4);
    s += v.x + v.y + v.z + v.w;
    ss += v.x * v.x + v.y * v.y + v.z * v.z + v.w * v.w;
  }
#pragma unroll
  for (int off = 32; off > 0; off >>= 1) {
    s += __shfl_xor(s, off, 64);
    ss += __shfl_xor(ss, off, 64);
  }
  if ((tid & 63) == 0) { red[tid >> 6] = s; red[4 + (tid >> 6)] = ss; }
  __syncthreads();
  float S = red[0] + red[1] + red[2] + red[3];
  float SS = red[4] + red[5] + red[6] + red[7];
  float mean = S * (1.f / 16384.f);
  float var = SS * (1.f / 16384.f) - mean * mean;
  float inv = rsqrtf(var + 1e-5f);
#pragma unroll
  for (int r = 0; r < 16; ++r) {
    int c = g * 16 + r;
    float a = inv * gw[c];
    float bb = gb[c] - mean * a;
    float4 v = *(const float4*)(xg + r * 1024 + tid * 4);
    short* tr = tile + r * 1032 + tid * 4;
    tr[0] = f2bf(fmaf(v.x, a, bb));
    tr[1] = f2bf(fmaf(v.y, a, bb));
    tr[2] = f2bf(fmaf(v.z, a, bb));
    tr[3] = f2bf(fmaf(v.w, a, bb));
  }
  __syncthreads();
  int r = tid & 15, tq = tid >> 4;
  int c = g * 16 + r;
  short* dst = hT + b * 1024 * 512 + c;
  const short* src = tile + r * 1032;
#pragma unroll
  for (int i = 0; i < 64; ++i) {
    int t = i * 16 + tq;
    dst[t * 512] = src[t];
  }
}

// ---------------- shared GEMM core: K=512, 128x128 tile, BK=32 ----------------
__device__ __forceinline__ void gemm_k512(
    const short* __restrict__ Ag, const short* __restrict__ Bg,
    short* lA, short* lB, int wid, int lane, v4f acc[4][4]) {
  int r4 = lane >> 2, seg = lane & 3;
  int wr = (wid >> 1) * 64, wc = (wid & 1) * 64;
  int c16 = lane & 15, q8 = (lane >> 4) * 8;
  const short* ga = Ag + (wid * 16 + r4) * 512 + seg * 8;
  const short* gbp = Bg + (wid * 16 + r4) * 512 + seg * 8;
  for (int kt = 0; kt < 16; ++kt) {
    int k0 = kt * 32;
    gload16(ga + k0, lA + wid * 512);
    gload16(ga + 64 * 512 + k0, lA + (wid + 4) * 512);
    gload16(gbp + k0, lB + wid * 512);
    gload16(gbp + 64 * 512 + k0, lB + (wid + 4) * 512);
    __syncthreads();
    v8s af[4], bf[4];
#pragma unroll
    for (int i = 0; i < 4; ++i)
      af[i] = *(const v8s*)(lA + (wr + i * 16 + c16) * 32 + q8);
#pragma unroll
    for (int j = 0; j < 4; ++j)
      bf[j] = *(const v8s*)(lB + (wc + j * 16 + c16) * 32 + q8);
#pragma unroll
    for (int i = 0; i < 4; ++i)
#pragma unroll
      for (int j = 0; j < 4; ++j)
        acc[i][j] = MFMA(af[i], bf[j], acc[i][j]);
    __syncthreads();
  }
}

// ---------------- QKV GEMM: M=n(8192), N=o(1536) ----------------
// Q pre-scaled by 0.125*log2(e) so attention can use raw v_exp_f32 (2^x).
__global__ __launch_bounds__(256) void qkv_gemm_kernel(
    const short* __restrict__ hT, const short* __restrict__ Wq,
    const float* __restrict__ bias2,
    short* __restrict__ Qb, short* __restrict__ Kb, short* __restrict__ Vb) {
  __shared__ __align__(16) short smem[17408];
  short* lA = smem;
  short* lB = smem + 4096;
  short* vt = smem;
  int bm = blockIdx.x & 63, bo = blockIdx.x >> 6;
  int tid = threadIdx.x, wid = tid >> 6, lane = tid & 63;
  int wr = (wid >> 1) * 64, wc = (wid & 1) * 64;
  int q = lane >> 4, c16 = lane & 15;
  v4f acc[4][4];
#pragma unroll
  for (int i = 0; i < 4; ++i)
#pragma unroll
    for (int j = 0; j < 4; ++j) acc[i][j] = (v4f){0.f, 0.f, 0.f, 0.f};
  gemm_k512(hT + bm * 128 * 512, Wq + bo * 128 * 512, lA, lB, wid, lane, acc);
  float bv[4];
#pragma unroll
  for (int j = 0; j < 4; ++j) bv[j] = bias2[bo * 128 + wc + j * 16 + c16];
  if (bo < 8) {
    short* dst = (bo < 4) ? Qb : Kb;
    float sc = (bo < 4) ? 0.18033688f : 1.f;  // 0.125 * log2(e) folded into Q
    int obase = (bo & 3) * 128 + wc;
#pragma unroll
    for (int j = 0; j < 4; ++j) {
      int ocol = obase + j * 16 + c16;
      int nh = ocol >> 6, cc = ocol & 63;
#pragma unroll
      for (int i = 0; i < 4; ++i)
#pragma unroll
        for (int rr = 0; rr < 4; ++rr) {
          int n = bm * 128 + wr + i * 16 + q * 4 + rr;
          int b_ = n >> 10, t = n & 1023;
          float v = (acc[i][j][rr] + bv[j]) * sc;
          dst[b_ * 524288 + nh * 65536 + t * 64 + cc] = f2bf(v);
        }
    }
  } else {
#pragma unroll
    for (int j = 0; j < 4; ++j) {
      int ol = wc + j * 16 + c16;
#pragma unroll
      for (int i = 0; i < 4; ++i)
#pragma unroll
        for (int rr = 0; rr < 4; ++rr) {
          int nl = wr + i * 16 + q * 4 + rr;
          vt[ol * 136 + nl] = f2bf(acc[i][j][rr] + bv[j]);
        }
    }
    __syncthreads();
    int ol = tid >> 1, hf = tid & 1;
    int ovg = (bo - 8) * 128 + ol;
    const short* src = vt + ol * 136 + hf * 64;
    short* dstv = Vb + ovg * 8192 + bm * 128 + hf * 64;
#pragma unroll
    for (int m = 0; m < 8; ++m)
      *(v8s*)(dstv + m * 8) = *(const v8s*)(src + m * 8);
  }
}

// ---------------- fused attention v6: v3 frame + v5 inner loop ----------------
// Grid 512: block = (head hb, 128-query tile tt). 512 threads = 8 waves;
// wave (w4 = wid&3) owns 32 queries, (chunk = wid>>2) owns s-half [chunk*512,+512).
// Inner: S^T = K*Q^T per-j, exp2 (log2e folded into Q), v_perm pack, one
// b64 P-write per (i,j). K double-buffered one tile ahead. Wave-private P
// tile stride 76 (no main-loop barriers); v3-style 2-chunk LDS combine.
__global__ __launch_bounds__(512, 4) void attn_kernel(
    const short* __restrict__ Qb, const short* __restrict__ Kb,
    const short* __restrict__ Vb, short* __restrict__ aT) {
  __shared__ __align__(16) short pb[8 * 32 * 76];  // 38912 B
  int hb = blockIdx.x >> 3, tt = blockIdx.x & 7;
  int b = hb >> 3, nh = hb & 7;
  int tid = threadIdx.x, wid = tid >> 6, lane = tid & 63;
  int chunk = wid >> 2, w4 = wid & 3;
  int q = lane >> 4, c16 = lane & 15;
  const short* Qh = Qb + hb * 65536;
  const short* Kh = Kb + hb * 65536;
  const short* Vh = Vb + nh * 64 * 8192 + b * 1024;
  int t0 = tt * 128 + w4 * 32;
  int sbase = chunk * 512;
  v8s qf[2][2];
#pragma unroll
  for (int i = 0; i < 2; ++i)
#pragma unroll
    for (int kk = 0; kk < 2; ++kk)
      qf[i][kk] = *(const v8s*)(Qh + (t0 + i * 16 + c16) * 64 + kk * 32 + q * 8);
  v4f of[2][4];
  float lsum[2] = {0.f, 0.f};
#pragma unroll
  for (int i = 0; i < 2; ++i)
#pragma unroll
    for (int j = 0; j < 4; ++j) of[i][j] = (v4f){0.f, 0.f, 0.f, 0.f};
  short* pw = pb + wid * 2432;
  // K fragments for tile 0
  v8s kf[2][4][2];
#pragma unroll
  for (int j = 0; j < 4; ++j)
#pragma unroll
    for (int kk = 0; kk < 2; ++kk)
      kf[0][j][kk] =
          *(const v8s*)(Kh + (sbase + j * 16 + c16) * 64 + kk * 32 + q * 8);
#pragma unroll 2
  for (int st = 0; st < 8; ++st) {
    int cur = st & 1, nxt = cur ^ 1;
    int s0 = sbase + st * 64;
    // K for NEXT tile: in flight across this tile's compute
    if (st < 7) {
#pragma unroll
      for (int j = 0; j < 4; ++j)
#pragma unroll
        for (int kk = 0; kk < 2; ++kk)
          kf[nxt][j][kk] =
              *(const v8s*)(Kh + (s0 + 64 + j * 16 + c16) * 64 + kk * 32 + q * 8);
    }
    // per-j: S^T = K Q^T (keys on C rows -> s-contiguous), exp2 + pack + write
#pragma unroll
    for (int j = 0; j < 4; ++j) {
      v4f s0v = (v4f){0.f, 0.f, 0.f, 0.f};
      s0v = MFMA(kf[cur][j][0], qf[0][0], s0v);
      s0v = MFMA(kf[cur][j][1], qf[0][1], s0v);
      v4f s1v = (v4f){0.f, 0.f, 0.f, 0.f};
      s1v = MFMA(kf[cur][j][0], qf[1][0], s1v);
      s1v = MFMA(kf[cur][j][1], qf[1][1], s1v);
      float p00 = __builtin_amdgcn_exp2f(s0v[0]);
      float p01 = __builtin_amdgcn_exp2f(s0v[1]);
      float p02 = __builtin_amdgcn_exp2f(s0v[2]);
      float p03 = __builtin_amdgcn_exp2f(s0v[3]);
      lsum[0] += (p00 + p01) + (p02 + p03);
      uint2 pk0;
      pk0.x = pack2(p00, p01);
      pk0.y = pack2(p02, p03);
      *(uint2*)(pw + c16 * 76 + j * 16 + q * 4) = pk0;
      float p10 = __builtin_amdgcn_exp2f(s1v[0]);
      float p11 = __builtin_amdgcn_exp2f(s1v[1]);
      float p12 = __builtin_amdgcn_exp2f(s1v[2]);
      float p13 = __builtin_amdgcn_exp2f(s1v[3]);
      lsum[1] += (p10 + p11) + (p12 + p13);
      uint2 pk1;
      pk1.x = pack2(p10, p11);
      pk1.y = pack2(p12, p13);
      *(uint2*)(pw + (16 + c16) * 76 + j * 16 + q * 4) = pk1;
    }
    // V for this tile (post-exp position: QK/PV register peaks don't overlap)
    v8s vf[4][2];
#pragma unroll
    for (int j = 0; j < 4; ++j)
#pragma unroll
      for (int kk = 0; kk < 2; ++kk)
        vf[j][kk] = *(const v8s*)(Vh + (j * 16 + c16) * 8192 + s0 + kk * 32 + q * 8);
    // same-wave DS ordering: drain P writes before A-layout reads
    asm volatile("s_waitcnt lgkmcnt(0)" ::: "memory");
    v8s pa[2][2];
#pragma unroll
    for (int i = 0; i < 2; ++i)
#pragma unroll
      for (int kk = 0; kk < 2; ++kk)
        pa[i][kk] = *(const v8s*)(pw + (i * 16 + c16) * 76 + kk * 32 + q * 8);
    // O += P V^T
#pragma unroll
    for (int i = 0; i < 2; ++i)
#pragma unroll
      for (int j = 0; j < 4; ++j) {
        of[i][j] = MFMA(pa[i][0], vf[j][0], of[i][j]);
        of[i][j] = MFMA(pa[i][1], vf[j][1], of[i][j]);
      }
  }
  // l: sum across the 4 key-quad groups within the wave
#pragma unroll
  for (int i = 0; i < 2; ++i) {
    lsum[i] += __shfl_xor(lsum[i], 16, 64);
    lsum[i] += __shfl_xor(lsum[i], 32, 64);
  }
  // combine the two s-halves via LDS; slot per w4: 32x66 O + 32 l = 2144 floats
  float* ex = (float*)pb + w4 * 2144;
  __syncthreads();
  if (chunk == 1) {
#pragma unroll
    for (int i = 0; i < 2; ++i) {
#pragma unroll
      for (int j = 0; j < 4; ++j)
#pragma unroll
        for (int rr = 0; rr < 4; ++rr)
          ex[(i * 16 + q * 4 + rr) * 66 + j * 16 + c16] = of[i][j][rr];
      if (q == 0) ex[2112 + i * 16 + c16] = lsum[i];
    }
  }
  __syncthreads();
  if (chunk == 0) {
    short* base = aT + b * 1024 * 512 + nh * 64;
#pragma unroll
    for (int i = 0; i < 2; ++i)
#pragma unroll
      for (int rr = 0; rr < 4; ++rr) {
        int row = i * 16 + q * 4 + rr;
        float inv = 1.f / (__shfl(lsum[i], q * 4 + rr, 64) + ex[2112 + row]);
        int t = t0 + row;
#pragma unroll
        for (int j = 0; j < 4; ++j) {
          float v = (of[i][j][rr] + ex[row * 66 + j * 16 + c16]) * inv;
          base[t * 512 + j * 16 + c16] = f2bf(v);
        }
      }
  }
}

// ---------------- proj GEMM: M=o(512), N=n(8192), fused bias+residual ----------------
__global__ __launch_bounds__(256) void proj_gemm_kernel(
    const short* __restrict__ Wp, const short* __restrict__ aT,
    const float* __restrict__ pbias, const float* __restrict__ x,
    float* __restrict__ out) {
  __shared__ __align__(16) short smem[8192];
  short* lA = smem;
  short* lB = smem + 4096;
  int bm = blockIdx.x & 3, bn = blockIdx.x >> 2;
  int tid = threadIdx.x, wid = tid >> 6, lane = tid & 63;
  int wr = (wid >> 1) * 64, wc = (wid & 1) * 64;
  int q = lane >> 4, c16 = lane & 15;
  v4f acc[4][4];
#pragma unroll
  for (int i = 0; i < 4; ++i)
#pragma unroll
    for (int j = 0; j < 4; ++j) acc[i][j] = (v4f){0.f, 0.f, 0.f, 0.f};
  gemm_k512(Wp + bm * 128 * 512, aT + bn * 128 * 512, lA, lB, wid, lane, acc);
  int colOff[4];
#pragma unroll
  for (int j = 0; j < 4; ++j) {
    int n = bn * 128 + wc + j * 16 + c16;
    colOff[j] = (n >> 10) * 524288 + (n & 1023);
  }
#pragma unroll
  for (int i = 0; i < 4; ++i)
#pragma unroll
    for (int rr = 0; rr < 4; ++rr) {
      int o = bm * 128 + wr + i * 16 + q * 4 + rr;
      float bs = pbias[o];
      int ro = o * 1024;
#pragma unroll
      for (int j = 0; j < 4; ++j) {
        int a = colOff[j] + ro;
        out[a] = acc[i][j][rr] + bs + x[a];
      }
    }
}

extern "C" void kernel_launch(void* const* d_in, const int* in_sizes, int n_in,
                              void* d_out, int out_size, void* d_ws, size_t ws_size,
                              hipStream_t stream) {
  const float* x = (const float*)d_in[0];
  const float* nw = (const float*)d_in[1];
  const float* nb = (const float*)d_in[2];
  const float* qkvw = (const float*)d_in[3];
  const float* qkvb = (const float*)d_in[4];
  const float* projw = (const float*)d_in[5];
  const float* projb = (const float*)d_in[6];
  float* out = (float*)d_out;
  char* w = (char*)d_ws;
  short* hT = (short*)(w);
  short* aT = (short*)(w + 8388608);
  short* Qb = (short*)(w + 16777216);
  short* Kb = (short*)(w + 25165824);
  short* Vb = (short*)(w + 33554432);
  short* Wq2 = (short*)(w + 41943040);
  short* Wp2 = (short*)(w + 43515904);
  float* b2 = (float*)(w + 44040192);

  hipLaunchKernelGGL(prep_kernel, dim3(4096), dim3(256), 0, stream,
                     qkvw, qkvb, projw, Wq2, Wp2, b2);
  hipLaunchKernelGGL(groupnorm_kernel, dim3(256), dim3(256), 0, stream, x, nw, nb, hT);
  hipLaunchKernelGGL(qkv_gemm_kernel, dim3(768), dim3(256), 0, stream,
                     hT, Wq2, b2, Qb, Kb, Vb);
  hipLaunchKernelGGL(attn_kernel, dim3(512), dim3(512), 0, stream, Qb, Kb, Vb, aT);
  hipLaunchKernelGGL(proj_gemm_kernel, dim3(256), dim3(256), 0, stream,
                     Wp2, aT, projb, x, out);
}

// Round 7
// 188.268 us; speedup vs baseline: 1.3927x; 1.3927x over previous
//
#include <hip/hip_runtime.h>
#include <stdint.h>

typedef short v8s __attribute__((ext_vector_type(8)));
typedef float v4f __attribute__((ext_vector_type(4)));

#define MFMA(a, b, c) __builtin_amdgcn_mfma_f32_16x16x32_bf16((a), (b), (c), 0, 0, 0)

__device__ __forceinline__ short f2bf(float f) {
  union { float f; uint32_t u; } v; v.f = f;
  uint32_t r = v.u + 0x7fffu + ((v.u >> 16) & 1u);
  return (short)(r >> 16);
}

// pack two fp32 -> two bf16 (truncate) in one v_perm_b32
__device__ __forceinline__ uint32_t pack2(float a, float b) {
  union { float f; uint32_t u; } ua, ub; ua.f = a; ub.f = b;
  return __builtin_amdgcn_perm(ub.u, ua.u, 0x07060302u);
}

__device__ __forceinline__ void gload16(const void* g, void* l) {
  __builtin_amdgcn_global_load_lds((const __attribute__((address_space(1))) void*)g,
                                   (__attribute__((address_space(3))) void*)l,
                                   16, 0, 0);
}

// ------- merged prep (blocks 256..4351) + groupnorm (blocks 0..255) -------
__global__ __launch_bounds__(256) void prep_gn_kernel(
    const float* __restrict__ qkvw, const float* __restrict__ qkvb,
    const float* __restrict__ projw,
    short* __restrict__ Wq, short* __restrict__ Wp, float* __restrict__ bias2,
    const float* __restrict__ x, const float* __restrict__ gw,
    const float* __restrict__ gb, short* __restrict__ hT) {
  __shared__ float red[8];
  __shared__ short tile[16 * 1032];
  int tid = threadIdx.x;
  if (blockIdx.x >= 256) {
    // ---- prep: permute + convert weights to bf16 ----
    int idx = (blockIdx.x - 256) * 256 + tid;
    if (idx < 1536 * 512) {
      int r = idx >> 9, c = idx & 511;
      int sec = r >> 9;            // 0=q, 1=k, 2=v
      int rr = r & 511;
      int nh = rr >> 6, cc = rr & 63;
      int o = nh * 192 + sec * 64 + cc;
      Wq[idx] = f2bf(qkvw[o * 512 + c]);
      if (c == 0) bias2[r] = qkvb[o];
    } else {
      int j = idx - 1536 * 512;
      if (j < 512 * 512) Wp[j] = f2bf(projw[j]);
    }
    return;
  }
  // ---- groupnorm: writes hT[n=b*1024+t][c] bf16 ----
  int b = blockIdx.x >> 5, g = blockIdx.x & 31;
  const float* xg = x + (b * 512 + g * 16) * 1024;
  float s = 0.f, ss = 0.f;
#pragma unroll
  for (int r = 0; r < 16; ++r) {
    float4 v = *(const float4*)(xg + r * 1024 + tid * 4);
    s += v.x + v.y + v.z + v.w;
    ss += v.x * v.x + v.y * v.y + v.z * v.z + v.w * v.w;
  }
#pragma unroll
  for (int off = 32; off > 0; off >>= 1) {
    s += __shfl_xor(s, off, 64);
    ss += __shfl_xor(ss, off, 64);
  }
  if ((tid & 63) == 0) { red[tid >> 6] = s; red[4 + (tid >> 6)] = ss; }
  __syncthreads();
  float S = red[0] + red[1] + red[2] + red[3];
  float SS = red[4] + red[5] + red[6] + red[7];
  float mean = S * (1.f / 16384.f);
  float var = SS * (1.f / 16384.f) - mean * mean;
  float inv = rsqrtf(var + 1e-5f);
#pragma unroll
  for (int r = 0; r < 16; ++r) {
    int c = g * 16 + r;
    float a = inv * gw[c];
    float bb = gb[c] - mean * a;
    float4 v = *(const float4*)(xg + r * 1024 + tid * 4);
    short* tr = tile + r * 1032 + tid * 4;
    tr[0] = f2bf(fmaf(v.x, a, bb));
    tr[1] = f2bf(fmaf(v.y, a, bb));
    tr[2] = f2bf(fmaf(v.z, a, bb));
    tr[3] = f2bf(fmaf(v.w, a, bb));
  }
  __syncthreads();
  int r = tid & 15, tq = tid >> 4;
  int c = g * 16 + r;
  short* dst = hT + b * 1024 * 512 + c;
  const short* src = tile + r * 1032;
#pragma unroll
  for (int i = 0; i < 64; ++i) {
    int t = i * 16 + tq;
    dst[t * 512] = src[t];
  }
}

// ---------------- shared GEMM core: K=512, 128x128 tile, BK=32 ----------------
__device__ __forceinline__ void gemm_k512(
    const short* __restrict__ Ag, const short* __restrict__ Bg,
    short* lA, short* lB, int wid, int lane, v4f acc[4][4]) {
  int r4 = lane >> 2, seg = lane & 3;
  int wr = (wid >> 1) * 64, wc = (wid & 1) * 64;
  int c16 = lane & 15, q8 = (lane >> 4) * 8;
  const short* ga = Ag + (wid * 16 + r4) * 512 + seg * 8;
  const short* gbp = Bg + (wid * 16 + r4) * 512 + seg * 8;
  for (int kt = 0; kt < 16; ++kt) {
    int k0 = kt * 32;
    gload16(ga + k0, lA + wid * 512);
    gload16(ga + 64 * 512 + k0, lA + (wid + 4) * 512);
    gload16(gbp + k0, lB + wid * 512);
    gload16(gbp + 64 * 512 + k0, lB + (wid + 4) * 512);
    __syncthreads();
    v8s af[4], bf[4];
#pragma unroll
    for (int i = 0; i < 4; ++i)
      af[i] = *(const v8s*)(lA + (wr + i * 16 + c16) * 32 + q8);
#pragma unroll
    for (int j = 0; j < 4; ++j)
      bf[j] = *(const v8s*)(lB + (wc + j * 16 + c16) * 32 + q8);
#pragma unroll
    for (int i = 0; i < 4; ++i)
#pragma unroll
      for (int j = 0; j < 4; ++j)
        acc[i][j] = MFMA(af[i], bf[j], acc[i][j]);
    __syncthreads();
  }
}

// ---------------- QKV GEMM: M=n(8192), N=o(1536) ----------------
// Q pre-scaled by 0.125*log2(e) so attention can use raw v_exp_f32 (2^x).
__global__ __launch_bounds__(256) void qkv_gemm_kernel(
    const short* __restrict__ hT, const short* __restrict__ Wq,
    const float* __restrict__ bias2,
    short* __restrict__ Qb, short* __restrict__ Kb, short* __restrict__ Vb) {
  __shared__ __align__(16) short smem[17408];
  short* lA = smem;
  short* lB = smem + 4096;
  short* vt = smem;
  int bm = blockIdx.x & 63, bo = blockIdx.x >> 6;
  int tid = threadIdx.x, wid = tid >> 6, lane = tid & 63;
  int wr = (wid >> 1) * 64, wc = (wid & 1) * 64;
  int q = lane >> 4, c16 = lane & 15;
  v4f acc[4][4];
#pragma unroll
  for (int i = 0; i < 4; ++i)
#pragma unroll
    for (int j = 0; j < 4; ++j) acc[i][j] = (v4f){0.f, 0.f, 0.f, 0.f};
  gemm_k512(hT + bm * 128 * 512, Wq + bo * 128 * 512, lA, lB, wid, lane, acc);
  float bv[4];
#pragma unroll
  for (int j = 0; j < 4; ++j) bv[j] = bias2[bo * 128 + wc + j * 16 + c16];
  if (bo < 8) {
    short* dst = (bo < 4) ? Qb : Kb;
    float sc = (bo < 4) ? 0.18033688f : 1.f;  // 0.125 * log2(e) folded into Q
    int obase = (bo & 3) * 128 + wc;
#pragma unroll
    for (int j = 0; j < 4; ++j) {
      int ocol = obase + j * 16 + c16;
      int nh = ocol >> 6, cc = ocol & 63;
#pragma unroll
      for (int i = 0; i < 4; ++i)
#pragma unroll
        for (int rr = 0; rr < 4; ++rr) {
          int n = bm * 128 + wr + i * 16 + q * 4 + rr;
          int b_ = n >> 10, t = n & 1023;
          float v = (acc[i][j][rr] + bv[j]) * sc;
          dst[b_ * 524288 + nh * 65536 + t * 64 + cc] = f2bf(v);
        }
    }
  } else {
#pragma unroll
    for (int j = 0; j < 4; ++j) {
      int ol = wc + j * 16 + c16;
#pragma unroll
      for (int i = 0; i < 4; ++i)
#pragma unroll
        for (int rr = 0; rr < 4; ++rr) {
          int nl = wr + i * 16 + q * 4 + rr;
          vt[ol * 136 + nl] = f2bf(acc[i][j][rr] + bv[j]);
        }
    }
    __syncthreads();
    int ol = tid >> 1, hf = tid & 1;
    int ovg = (bo - 8) * 128 + ol;
    const short* src = vt + ol * 136 + hf * 64;
    short* dstv = Vb + ovg * 8192 + bm * 128 + hf * 64;
#pragma unroll
    for (int m = 0; m < 8; ++m)
      *(v8s*)(dstv + m * 8) = *(const v8s*)(src + m * 8);
  }
}

// ---------------- fused attention v7: R3 frame + R4 inner, NO dbuf ----------
// Grid 512: block = (head hb, 128-query tile tt). 512 threads = 8 waves;
// wave (w4 = wid&3) owns 32 queries, (chunk = wid>>2) owns s-half.
// Inner: S^T = K*Q^T per-j, exp2 (log2e folded into Q), v_perm pack, one
// b64 P-write per (i,j). K loaded fresh per tile (dbuf spills — R5/R6).
// Wave-private P tile stride 76, no main-loop barriers; 2-chunk LDS combine.
__global__ __launch_bounds__(512, 4) void attn_kernel(
    const short* __restrict__ Qb, const short* __restrict__ Kb,
    const short* __restrict__ Vb, short* __restrict__ aT) {
  __shared__ __align__(16) short pb[8 * 32 * 76];  // 38912 B
  int hb = blockIdx.x >> 3, tt = blockIdx.x & 7;
  int b = hb >> 3, nh = hb & 7;
  int tid = threadIdx.x, wid = tid >> 6, lane = tid & 63;
  int chunk = wid >> 2, w4 = wid & 3;
  int q = lane >> 4, c16 = lane & 15;
  const short* Qh = Qb + hb * 65536;
  const short* Kh = Kb + hb * 65536;
  const short* Vh = Vb + nh * 64 * 8192 + b * 1024;
  int t0 = tt * 128 + w4 * 32;
  int sbase = chunk * 512;
  v8s qf[2][2];
#pragma unroll
  for (int i = 0; i < 2; ++i)
#pragma unroll
    for (int kk = 0; kk < 2; ++kk)
      qf[i][kk] = *(const v8s*)(Qh + (t0 + i * 16 + c16) * 64 + kk * 32 + q * 8);
  v4f of[2][4];
  float lsum[2] = {0.f, 0.f};
#pragma unroll
  for (int i = 0; i < 2; ++i)
#pragma unroll
    for (int j = 0; j < 4; ++j) of[i][j] = (v4f){0.f, 0.f, 0.f, 0.f};
  short* pw = pb + wid * 2432;
#pragma unroll 1
  for (int st = 0; st < 8; ++st) {
    int s0 = sbase + st * 64;
    // K fragments for this tile (fresh load; dbuf spills on this toolchain)
    v8s kf[4][2];
#pragma unroll
    for (int j = 0; j < 4; ++j)
#pragma unroll
      for (int kk = 0; kk < 2; ++kk)
        kf[j][kk] = *(const v8s*)(Kh + (s0 + j * 16 + c16) * 64 + kk * 32 + q * 8);
    // per-j: S^T = K Q^T (keys on C rows -> s-contiguous), exp2 + pack + write
#pragma unroll
    for (int j = 0; j < 4; ++j) {
      v4f s0v = (v4f){0.f, 0.f, 0.f, 0.f};
      s0v = MFMA(kf[j][0], qf[0][0], s0v);
      s0v = MFMA(kf[j][1], qf[0][1], s0v);
      v4f s1v = (v4f){0.f, 0.f, 0.f, 0.f};
      s1v = MFMA(kf[j][0], qf[1][0], s1v);
      s1v = MFMA(kf[j][1], qf[1][1], s1v);
      float p00 = __builtin_amdgcn_exp2f(s0v[0]);
      float p01 = __builtin_amdgcn_exp2f(s0v[1]);
      float p02 = __builtin_amdgcn_exp2f(s0v[2]);
      float p03 = __builtin_amdgcn_exp2f(s0v[3]);
      lsum[0] += (p00 + p01) + (p02 + p03);
      uint2 pk0;
      pk0.x = pack2(p00, p01);
      pk0.y = pack2(p02, p03);
      *(uint2*)(pw + c16 * 76 + j * 16 + q * 4) = pk0;
      float p10 = __builtin_amdgcn_exp2f(s1v[0]);
      float p11 = __builtin_amdgcn_exp2f(s1v[1]);
      float p12 = __builtin_amdgcn_exp2f(s1v[2]);
      float p13 = __builtin_amdgcn_exp2f(s1v[3]);
      lsum[1] += (p10 + p11) + (p12 + p13);
      uint2 pk1;
      pk1.x = pack2(p10, p11);
      pk1.y = pack2(p12, p13);
      *(uint2*)(pw + (16 + c16) * 76 + j * 16 + q * 4) = pk1;
    }
    // V for this tile (post-exp position: QK/PV register peaks don't overlap)
    v8s vf[4][2];
#pragma unroll
    for (int j = 0; j < 4; ++j)
#pragma unroll
      for (int kk = 0; kk < 2; ++kk)
        vf[j][kk] = *(const v8s*)(Vh + (j * 16 + c16) * 8192 + s0 + kk * 32 + q * 8);
    // same-wave DS ordering: drain P writes before A-layout reads
    asm volatile("s_waitcnt lgkmcnt(0)" ::: "memory");
    v8s pa[2][2];
#pragma unroll
    for (int i = 0; i < 2; ++i)
#pragma unroll
      for (int kk = 0; kk < 2; ++kk)
        pa[i][kk] = *(const v8s*)(pw + (i * 16 + c16) * 76 + kk * 32 + q * 8);
    // O += P V^T
#pragma unroll
    for (int i = 0; i < 2; ++i)
#pragma unroll
      for (int j = 0; j < 4; ++j) {
        of[i][j] = MFMA(pa[i][0], vf[j][0], of[i][j]);
        of[i][j] = MFMA(pa[i][1], vf[j][1], of[i][j]);
      }
  }
  // l: sum across the 4 key-quad groups within the wave
#pragma unroll
  for (int i = 0; i < 2; ++i) {
    lsum[i] += __shfl_xor(lsum[i], 16, 64);
    lsum[i] += __shfl_xor(lsum[i], 32, 64);
  }
  // combine the two s-halves via LDS; slot per w4: 32x66 O + 32 l = 2144 floats
  float* ex = (float*)pb + w4 * 2144;
  __syncthreads();
  if (chunk == 1) {
#pragma unroll
    for (int i = 0; i < 2; ++i) {
#pragma unroll
      for (int j = 0; j < 4; ++j)
#pragma unroll
        for (int rr = 0; rr < 4; ++rr)
          ex[(i * 16 + q * 4 + rr) * 66 + j * 16 + c16] = of[i][j][rr];
      if (q == 0) ex[2112 + i * 16 + c16] = lsum[i];
    }
  }
  __syncthreads();
  if (chunk == 0) {
    short* base = aT + b * 1024 * 512 + nh * 64;
#pragma unroll
    for (int i = 0; i < 2; ++i)
#pragma unroll
      for (int rr = 0; rr < 4; ++rr) {
        int row = i * 16 + q * 4 + rr;
        float inv = 1.f / (__shfl(lsum[i], q * 4 + rr, 64) + ex[2112 + row]);
        int t = t0 + row;
#pragma unroll
        for (int j = 0; j < 4; ++j) {
          float v = (of[i][j][rr] + ex[row * 66 + j * 16 + c16]) * inv;
          base[t * 512 + j * 16 + c16] = f2bf(v);
        }
      }
  }
}

// ---------------- proj GEMM: M=o(512), N=n(8192), fused bias+residual ----------------
__global__ __launch_bounds__(256) void proj_gemm_kernel(
    const short* __restrict__ Wp, const short* __restrict__ aT,
    const float* __restrict__ pbias, const float* __restrict__ x,
    float* __restrict__ out) {
  __shared__ __align__(16) short smem[8192];
  short* lA = smem;
  short* lB = smem + 4096;
  int bm = blockIdx.x & 3, bn = blockIdx.x >> 2;
  int tid = threadIdx.x, wid = tid >> 6, lane = tid & 63;
  int wr = (wid >> 1) * 64, wc = (wid & 1) * 64;
  int q = lane >> 4, c16 = lane & 15;
  v4f acc[4][4];
#pragma unroll
  for (int i = 0; i < 4; ++i)
#pragma unroll
    for (int j = 0; j < 4; ++j) acc[i][j] = (v4f){0.f, 0.f, 0.f, 0.f};
  gemm_k512(Wp + bm * 128 * 512, aT + bn * 128 * 512, lA, lB, wid, lane, acc);
  int colOff[4];
#pragma unroll
  for (int j = 0; j < 4; ++j) {
    int n = bn * 128 + wc + j * 16 + c16;
    colOff[j] = (n >> 10) * 524288 + (n & 1023);
  }
#pragma unroll
  for (int i = 0; i < 4; ++i)
#pragma unroll
    for (int rr = 0; rr < 4; ++rr) {
      int o = bm * 128 + wr + i * 16 + q * 4 + rr;
      float bs = pbias[o];
      int ro = o * 1024;
#pragma unroll
      for (int j = 0; j < 4; ++j) {
        int a = colOff[j] + ro;
        out[a] = acc[i][j][rr] + bs + x[a];
      }
    }
}

extern "C" void kernel_launch(void* const* d_in, const int* in_sizes, int n_in,
                              void* d_out, int out_size, void* d_ws, size_t ws_size,
                              hipStream_t stream) {
  const float* x = (const float*)d_in[0];
  const float* nw = (const float*)d_in[1];
  const float* nb = (const float*)d_in[2];
  const float* qkvw = (const float*)d_in[3];
  const float* qkvb = (const float*)d_in[4];
  const float* projw = (const float*)d_in[5];
  const float* projb = (const float*)d_in[6];
  float* out = (float*)d_out;
  char* w = (char*)d_ws;
  short* hT = (short*)(w);
  short* aT = (short*)(w + 8388608);
  short* Qb = (short*)(w + 16777216);
  short* Kb = (short*)(w + 25165824);
  short* Vb = (short*)(w + 33554432);
  short* Wq2 = (short*)(w + 41943040);
  short* Wp2 = (short*)(w + 43515904);
  float* b2 = (float*)(w + 44040192);

  hipLaunchKernelGGL(prep_gn_kernel, dim3(4352), dim3(256), 0, stream,
                     qkvw, qkvb, projw, Wq2, Wp2, b2, x, nw, nb, hT);
  hipLaunchKernelGGL(qkv_gemm_kernel, dim3(768), dim3(256), 0, stream,
                     hT, Wq2, b2, Qb, Kb, Vb);
  hipLaunchKernelGGL(attn_kernel, dim3(512), dim3(512), 0, stream, Qb, Kb, Vb, aT);
  hipLaunchKernelGGL(proj_gemm_kernel, dim3(256), dim3(256), 0, stream,
                     Wp2, aT, projb, x, out);
}

// Round 8
// 163.116 us; speedup vs baseline: 1.6075x; 1.1542x over previous
//
#include <hip/hip_runtime.h>
#include <stdint.h>

typedef short v8s __attribute__((ext_vector_type(8)));
typedef float v4f __attribute__((ext_vector_type(4)));

#define MFMA(a, b, c) __builtin_amdgcn_mfma_f32_16x16x32_bf16((a), (b), (c), 0, 0, 0)

__device__ __forceinline__ short f2bf(float f) {
  union { float f; uint32_t u; } v; v.f = f;
  uint32_t r = v.u + 0x7fffu + ((v.u >> 16) & 1u);
  return (short)(r >> 16);
}

// pack two fp32 -> two bf16 (truncate) in one v_perm_b32
__device__ __forceinline__ uint32_t pack2(float a, float b) {
  union { float f; uint32_t u; } ua, ub; ua.f = a; ub.f = b;
  return __builtin_amdgcn_perm(ub.u, ua.u, 0x07060302u);
}

__device__ __forceinline__ void gload16(const void* g, void* l) {
  __builtin_amdgcn_global_load_lds((const __attribute__((address_space(1))) void*)g,
                                   (__attribute__((address_space(3))) void*)l,
                                   16, 0, 0);
}

// ------- merged prep (blocks 256..4351) + groupnorm (blocks 0..255) -------
__global__ __launch_bounds__(256) void prep_gn_kernel(
    const float* __restrict__ qkvw, const float* __restrict__ qkvb,
    const float* __restrict__ projw,
    short* __restrict__ Wq, short* __restrict__ Wp, float* __restrict__ bias2,
    const float* __restrict__ x, const float* __restrict__ gw,
    const float* __restrict__ gb, short* __restrict__ hT) {
  __shared__ float red[8];
  __shared__ short tile[16 * 1032];
  int tid = threadIdx.x;
  if (blockIdx.x >= 256) {
    int idx = (blockIdx.x - 256) * 256 + tid;
    if (idx < 1536 * 512) {
      int r = idx >> 9, c = idx & 511;
      int sec = r >> 9;            // 0=q, 1=k, 2=v
      int rr = r & 511;
      int nh = rr >> 6, cc = rr & 63;
      int o = nh * 192 + sec * 64 + cc;
      Wq[idx] = f2bf(qkvw[o * 512 + c]);
      if (c == 0) bias2[r] = qkvb[o];
    } else {
      int j = idx - 1536 * 512;
      if (j < 512 * 512) Wp[j] = f2bf(projw[j]);
    }
    return;
  }
  int b = blockIdx.x >> 5, g = blockIdx.x & 31;
  const float* xg = x + (b * 512 + g * 16) * 1024;
  float s = 0.f, ss = 0.f;
#pragma unroll
  for (int r = 0; r < 16; ++r) {
    float4 v = *(const float4*)(xg + r * 1024 + tid * 4);
    s += v.x + v.y + v.z + v.w;
    ss += v.x * v.x + v.y * v.y + v.z * v.z + v.w * v.w;
  }
#pragma unroll
  for (int off = 32; off > 0; off >>= 1) {
    s += __shfl_xor(s, off, 64);
    ss += __shfl_xor(ss, off, 64);
  }
  if ((tid & 63) == 0) { red[tid >> 6] = s; red[4 + (tid >> 6)] = ss; }
  __syncthreads();
  float S = red[0] + red[1] + red[2] + red[3];
  float SS = red[4] + red[5] + red[6] + red[7];
  float mean = S * (1.f / 16384.f);
  float var = SS * (1.f / 16384.f) - mean * mean;
  float inv = rsqrtf(var + 1e-5f);
#pragma unroll
  for (int r = 0; r < 16; ++r) {
    int c = g * 16 + r;
    float a = inv * gw[c];
    float bb = gb[c] - mean * a;
    float4 v = *(const float4*)(xg + r * 1024 + tid * 4);
    short* tr = tile + r * 1032 + tid * 4;
    tr[0] = f2bf(fmaf(v.x, a, bb));
    tr[1] = f2bf(fmaf(v.y, a, bb));
    tr[2] = f2bf(fmaf(v.z, a, bb));
    tr[3] = f2bf(fmaf(v.w, a, bb));
  }
  __syncthreads();
  int r = tid & 15, tq = tid >> 4;
  int c = g * 16 + r;
  short* dst = hT + b * 1024 * 512 + c;
  const short* src = tile + r * 1032;
#pragma unroll
  for (int i = 0; i < 64; ++i) {
    int t = i * 16 + tq;
    dst[t * 512] = src[t];
  }
}

// ---------------- shared GEMM core: K=512, 128x128 tile, BK=32 ----------------
__device__ __forceinline__ void gemm_k512(
    const short* __restrict__ Ag, const short* __restrict__ Bg,
    short* lA, short* lB, int wid, int lane, v4f acc[4][4]) {
  int r4 = lane >> 2, seg = lane & 3;
  int wr = (wid >> 1) * 64, wc = (wid & 1) * 64;
  int c16 = lane & 15, q8 = (lane >> 4) * 8;
  const short* ga = Ag + (wid * 16 + r4) * 512 + seg * 8;
  const short* gbp = Bg + (wid * 16 + r4) * 512 + seg * 8;
  for (int kt = 0; kt < 16; ++kt) {
    int k0 = kt * 32;
    gload16(ga + k0, lA + wid * 512);
    gload16(ga + 64 * 512 + k0, lA + (wid + 4) * 512);
    gload16(gbp + k0, lB + wid * 512);
    gload16(gbp + 64 * 512 + k0, lB + (wid + 4) * 512);
    __syncthreads();
    v8s af[4], bf[4];
#pragma unroll
    for (int i = 0; i < 4; ++i)
      af[i] = *(const v8s*)(lA + (wr + i * 16 + c16) * 32 + q8);
#pragma unroll
    for (int j = 0; j < 4; ++j)
      bf[j] = *(const v8s*)(lB + (wc + j * 16 + c16) * 32 + q8);
#pragma unroll
    for (int i = 0; i < 4; ++i)
#pragma unroll
      for (int j = 0; j < 4; ++j)
        acc[i][j] = MFMA(af[i], bf[j], acc[i][j]);
    __syncthreads();
  }
}

// ---------------- QKV GEMM: M=n(8192), N=o(1536) ----------------
// Q pre-scaled by 0.125*log2(e) so attention can use raw v_exp_f32 (2^x).
__global__ __launch_bounds__(256) void qkv_gemm_kernel(
    const short* __restrict__ hT, const short* __restrict__ Wq,
    const float* __restrict__ bias2,
    short* __restrict__ Qb, short* __restrict__ Kb, short* __restrict__ Vb) {
  __shared__ __align__(16) short smem[17408];
  short* lA = smem;
  short* lB = smem + 4096;
  short* vt = smem;
  int bm = blockIdx.x & 63, bo = blockIdx.x >> 6;
  int tid = threadIdx.x, wid = tid >> 6, lane = tid & 63;
  int wr = (wid >> 1) * 64, wc = (wid & 1) * 64;
  int q = lane >> 4, c16 = lane & 15;
  v4f acc[4][4];
#pragma unroll
  for (int i = 0; i < 4; ++i)
#pragma unroll
    for (int j = 0; j < 4; ++j) acc[i][j] = (v4f){0.f, 0.f, 0.f, 0.f};
  gemm_k512(hT + bm * 128 * 512, Wq + bo * 128 * 512, lA, lB, wid, lane, acc);
  float bv[4];
#pragma unroll
  for (int j = 0; j < 4; ++j) bv[j] = bias2[bo * 128 + wc + j * 16 + c16];
  if (bo < 8) {
    short* dst = (bo < 4) ? Qb : Kb;
    float sc = (bo < 4) ? 0.18033688f : 1.f;  // 0.125 * log2(e) folded into Q
    int obase = (bo & 3) * 128 + wc;
#pragma unroll
    for (int j = 0; j < 4; ++j) {
      int ocol = obase + j * 16 + c16;
      int nh = ocol >> 6, cc = ocol & 63;
#pragma unroll
      for (int i = 0; i < 4; ++i)
#pragma unroll
        for (int rr = 0; rr < 4; ++rr) {
          int n = bm * 128 + wr + i * 16 + q * 4 + rr;
          int b_ = n >> 10, t = n & 1023;
          float v = (acc[i][j][rr] + bv[j]) * sc;
          dst[b_ * 524288 + nh * 65536 + t * 64 + cc] = f2bf(v);
        }
    }
  } else {
#pragma unroll
    for (int j = 0; j < 4; ++j) {
      int ol = wc + j * 16 + c16;
#pragma unroll
      for (int i = 0; i < 4; ++i)
#pragma unroll
        for (int rr = 0; rr < 4; ++rr) {
          int nl = wr + i * 16 + q * 4 + rr;
          vt[ol * 136 + nl] = f2bf(acc[i][j][rr] + bv[j]);
        }
    }
    __syncthreads();
    int ol = tid >> 1, hf = tid & 1;
    int ovg = (bo - 8) * 128 + ol;
    const short* src = vt + ol * 136 + hf * 64;
    short* dstv = Vb + ovg * 8192 + bm * 128 + hf * 64;
#pragma unroll
    for (int m = 0; m < 8; ++m)
      *(v8s*)(dstv + m * 8) = *(const v8s*)(src + m * 8);
  }
}

// ---------------- fused attention v8: LDS-staged K/V (GEMM-style) ------------
// Grid 512: block = (head hb, 128-query tile tt). 512 thr = 8 waves; wave
// (w4 = wid&3) owns 32 queries, (chunk = wid>>2) owns s-half. Per 64-key
// tile each chunk stages K (8KB) + V (8KB) into LDS via global_load_lds
// width-16 (4 coalesced wave-instrs/wave vs 16 scattered b128 gathers).
// XOR swizzle (chunk^=row&7) applied on the GLOBAL source address (write
// side is lane-contiguous by HW) -> frag ds_read_b128 hits optimal 8 dw/bank.
// Inner math + epilogue identical to v7 (exp2, pack2, wave-private P).
__global__ __launch_bounds__(512, 4) void attn_kernel(
    const short* __restrict__ Qb, const short* __restrict__ Kb,
    const short* __restrict__ Vb, short* __restrict__ aT) {
  __shared__ __align__(16) short lds[35840];  // 71680 B: K 16K + V 16K + P 38.9K
  int hb = blockIdx.x >> 3, tt = blockIdx.x & 7;
  int b = hb >> 3, nh = hb & 7;
  int tid = threadIdx.x, wid = tid >> 6, lane = tid & 63;
  int chunk = wid >> 2, w4 = wid & 3;
  int q = lane >> 4, c16 = lane & 15;
  const short* Qh = Qb + hb * 65536;
  const short* Kh = Kb + hb * 65536;
  const short* Vh = Vb + nh * 64 * 8192 + b * 1024;
  int t0 = tt * 128 + w4 * 32;
  int sbase = chunk * 512;
  short* Kst = lds + chunk * 4096;
  short* Vst = lds + 8192 + chunk * 4096;
  short* pw = lds + 16384 + wid * 2432;  // wave-private P, stride 76
  v8s qf[2][2];
#pragma unroll
  for (int i = 0; i < 2; ++i)
#pragma unroll
    for (int kk = 0; kk < 2; ++kk)
      qf[i][kk] = *(const v8s*)(Qh + (t0 + i * 16 + c16) * 64 + kk * 32 + q * 8);
  v4f of[2][4];
  float lsum[2] = {0.f, 0.f};
#pragma unroll
  for (int i = 0; i < 2; ++i)
#pragma unroll
    for (int j = 0; j < 4; ++j) of[i][j] = (v4f){0.f, 0.f, 0.f, 0.f};
  // staging indices: this wave covers 16B-chunks [w4*128 + l*64 + lane]
  int sidx0 = w4 * 128 + lane;       // l = 0
  int sidx1 = w4 * 128 + 64 + lane;  // l = 1
  int r0 = sidx0 >> 3, m0 = (sidx0 & 7) ^ (r0 & 7);
  int r1 = sidx1 >> 3, m1 = (sidx1 & 7) ^ (r1 & 7);
#pragma unroll 1
  for (int st = 0; st < 8; ++st) {
    int s0 = sbase + st * 64;
    // stage K-tile + V-tile for this chunk (coalesced, swizzled source)
    gload16(Kh + (s0 + r0) * 64 + m0 * 8, Kst + (w4 * 128) * 8);
    gload16(Kh + (s0 + r1) * 64 + m1 * 8, Kst + (w4 * 128 + 64) * 8);
    gload16(Vh + r0 * 8192 + s0 + m0 * 8, Vst + (w4 * 128) * 8);
    gload16(Vh + r1 * 8192 + s0 + m1 * 8, Vst + (w4 * 128 + 64) * 8);
    __syncthreads();  // drains vmcnt: staged data visible to all 8 waves
    // K fragments from LDS (swizzled chunk index)
    v8s kf[4][2];
#pragma unroll
    for (int j = 0; j < 4; ++j) {
      int row = j * 16 + c16;
#pragma unroll
      for (int kk = 0; kk < 2; ++kk) {
        int pc = (kk * 4 + q) ^ (c16 & 7);
        kf[j][kk] = *(const v8s*)(Kst + row * 64 + pc * 8);
      }
    }
    // per-j: S^T = K Q^T (keys on C rows -> s-contiguous), exp2 + pack + write
#pragma unroll
    for (int j = 0; j < 4; ++j) {
      v4f s0v = (v4f){0.f, 0.f, 0.f, 0.f};
      s0v = MFMA(kf[j][0], qf[0][0], s0v);
      s0v = MFMA(kf[j][1], qf[0][1], s0v);
      v4f s1v = (v4f){0.f, 0.f, 0.f, 0.f};
      s1v = MFMA(kf[j][0], qf[1][0], s1v);
      s1v = MFMA(kf[j][1], qf[1][1], s1v);
      float p00 = __builtin_amdgcn_exp2f(s0v[0]);
      float p01 = __builtin_amdgcn_exp2f(s0v[1]);
      float p02 = __builtin_amdgcn_exp2f(s0v[2]);
      float p03 = __builtin_amdgcn_exp2f(s0v[3]);
      lsum[0] += (p00 + p01) + (p02 + p03);
      uint2 pk0;
      pk0.x = pack2(p00, p01);
      pk0.y = pack2(p02, p03);
      *(uint2*)(pw + c16 * 76 + j * 16 + q * 4) = pk0;
      float p10 = __builtin_amdgcn_exp2f(s1v[0]);
      float p11 = __builtin_amdgcn_exp2f(s1v[1]);
      float p12 = __builtin_amdgcn_exp2f(s1v[2]);
      float p13 = __builtin_amdgcn_exp2f(s1v[3]);
      lsum[1] += (p10 + p11) + (p12 + p13);
      uint2 pk1;
      pk1.x = pack2(p10, p11);
      pk1.y = pack2(p12, p13);
      *(uint2*)(pw + (16 + c16) * 76 + j * 16 + q * 4) = pk1;
    }
    // V fragments from LDS (same swizzle; row = channel)
    v8s vf[4][2];
#pragma unroll
    for (int j = 0; j < 4; ++j) {
      int row = j * 16 + c16;
#pragma unroll
      for (int kk = 0; kk < 2; ++kk) {
        int pc = (kk * 4 + q) ^ (c16 & 7);
        vf[j][kk] = *(const v8s*)(Vst + row * 64 + pc * 8);
      }
    }
    // same-wave DS ordering: drain P writes (and frag reads) before pa reads
    asm volatile("s_waitcnt lgkmcnt(0)" ::: "memory");
    v8s pa[2][2];
#pragma unroll
    for (int i = 0; i < 2; ++i)
#pragma unroll
      for (int kk = 0; kk < 2; ++kk)
        pa[i][kk] = *(const v8s*)(pw + (i * 16 + c16) * 76 + kk * 32 + q * 8);
    // O += P V^T
#pragma unroll
    for (int i = 0; i < 2; ++i)
#pragma unroll
      for (int j = 0; j < 4; ++j) {
        of[i][j] = MFMA(pa[i][0], vf[j][0], of[i][j]);
        of[i][j] = MFMA(pa[i][1], vf[j][1], of[i][j]);
      }
    __syncthreads();  // protect staging buffers before next-tile overwrite
  }
  // l: sum across the 4 key-quad groups within the wave
#pragma unroll
  for (int i = 0; i < 2; ++i) {
    lsum[i] += __shfl_xor(lsum[i], 16, 64);
    lsum[i] += __shfl_xor(lsum[i], 32, 64);
  }
  // combine the two s-halves via LDS (P region); slot per w4: 32x66 O + 32 l
  float* ex = (float*)(lds + 16384) + w4 * 2144;
  __syncthreads();
  if (chunk == 1) {
#pragma unroll
    for (int i = 0; i < 2; ++i) {
#pragma unroll
      for (int j = 0; j < 4; ++j)
#pragma unroll
        for (int rr = 0; rr < 4; ++rr)
          ex[(i * 16 + q * 4 + rr) * 66 + j * 16 + c16] = of[i][j][rr];
      if (q == 0) ex[2112 + i * 16 + c16] = lsum[i];
    }
  }
  __syncthreads();
  if (chunk == 0) {
    short* base = aT + b * 1024 * 512 + nh * 64;
#pragma unroll
    for (int i = 0; i < 2; ++i)
#pragma unroll
      for (int rr = 0; rr < 4; ++rr) {
        int row = i * 16 + q * 4 + rr;
        float inv = 1.f / (__shfl(lsum[i], q * 4 + rr, 64) + ex[2112 + row]);
        int t = t0 + row;
#pragma unroll
        for (int j = 0; j < 4; ++j) {
          float v = (of[i][j][rr] + ex[row * 66 + j * 16 + c16]) * inv;
          base[t * 512 + j * 16 + c16] = f2bf(v);
        }
      }
  }
}

// ---------------- proj GEMM: M=o(512), N=n(8192), fused bias+residual ----------------
__global__ __launch_bounds__(256) void proj_gemm_kernel(
    const short* __restrict__ Wp, const short* __restrict__ aT,
    const float* __restrict__ pbias, const float* __restrict__ x,
    float* __restrict__ out) {
  __shared__ __align__(16) short smem[8192];
  short* lA = smem;
  short* lB = smem + 4096;
  int bm = blockIdx.x & 3, bn = blockIdx.x >> 2;
  int tid = threadIdx.x, wid = tid >> 6, lane = tid & 63;
  int wr = (wid >> 1) * 64, wc = (wid & 1) * 64;
  int q = lane >> 4, c16 = lane & 15;
  v4f acc[4][4];
#pragma unroll
  for (int i = 0; i < 4; ++i)
#pragma unroll
    for (int j = 0; j < 4; ++j) acc[i][j] = (v4f){0.f, 0.f, 0.f, 0.f};
  gemm_k512(Wp + bm * 128 * 512, aT + bn * 128 * 512, lA, lB, wid, lane, acc);
  int colOff[4];
#pragma unroll
  for (int j = 0; j < 4; ++j) {
    int n = bn * 128 + wc + j * 16 + c16;
    colOff[j] = (n >> 10) * 524288 + (n & 1023);
  }
#pragma unroll
  for (int i = 0; i < 4; ++i)
#pragma unroll
    for (int rr = 0; rr < 4; ++rr) {
      int o = bm * 128 + wr + i * 16 + q * 4 + rr;
      float bs = pbias[o];
      int ro = o * 1024;
#pragma unroll
      for (int j = 0; j < 4; ++j) {
        int a = colOff[j] + ro;
        out[a] = acc[i][j][rr] + bs + x[a];
      }
    }
}

extern "C" void kernel_launch(void* const* d_in, const int* in_sizes, int n_in,
                              void* d_out, int out_size, void* d_ws, size_t ws_size,
                              hipStream_t stream) {
  const float* x = (const float*)d_in[0];
  const float* nw = (const float*)d_in[1];
  const float* nb = (const float*)d_in[2];
  const float* qkvw = (const float*)d_in[3];
  const float* qkvb = (const float*)d_in[4];
  const float* projw = (const float*)d_in[5];
  const float* projb = (const float*)d_in[6];
  float* out = (float*)d_out;
  char* w = (char*)d_ws;
  short* hT = (short*)(w);
  short* aT = (short*)(w + 8388608);
  short* Qb = (short*)(w + 16777216);
  short* Kb = (short*)(w + 25165824);
  short* Vb = (short*)(w + 33554432);
  short* Wq2 = (short*)(w + 41943040);
  short* Wp2 = (short*)(w + 43515904);
  float* b2 = (float*)(w + 44040192);

  hipLaunchKernelGGL(prep_gn_kernel, dim3(4352), dim3(256), 0, stream,
                     qkvw, qkvb, projw, Wq2, Wp2, b2, x, nw, nb, hT);
  hipLaunchKernelGGL(qkv_gemm_kernel, dim3(768), dim3(256), 0, stream,
                     hT, Wq2, b2, Qb, Kb, Vb);
  hipLaunchKernelGGL(attn_kernel, dim3(512), dim3(512), 0, stream, Qb, Kb, Vb, aT);
  hipLaunchKernelGGL(proj_gemm_kernel, dim3(256), dim3(256), 0, stream,
                     Wp2, aT, projb, x, out);
}

// Round 9
// 160.103 us; speedup vs baseline: 1.6377x; 1.0188x over previous
//
#include <hip/hip_runtime.h>
#include <stdint.h>

typedef short v8s __attribute__((ext_vector_type(8)));
typedef float v4f __attribute__((ext_vector_type(4)));

#define MFMA(a, b, c) __builtin_amdgcn_mfma_f32_16x16x32_bf16((a), (b), (c), 0, 0, 0)

__device__ __forceinline__ short f2bf(float f) {
  union { float f; uint32_t u; } v; v.f = f;
  uint32_t r = v.u + 0x7fffu + ((v.u >> 16) & 1u);
  return (short)(r >> 16);
}

// pack two fp32 -> two bf16 (truncate) in one v_perm_b32
__device__ __forceinline__ uint32_t pack2(float a, float b) {
  union { float f; uint32_t u; } ua, ub; ua.f = a; ub.f = b;
  return __builtin_amdgcn_perm(ub.u, ua.u, 0x07060302u);
}

__device__ __forceinline__ void gload16(const void* g, void* l) {
  __builtin_amdgcn_global_load_lds((const __attribute__((address_space(1))) void*)g,
                                   (__attribute__((address_space(3))) void*)l,
                                   16, 0, 0);
}

// ------- merged prep (blocks 256..4351) + groupnorm (blocks 0..255) -------
__global__ __launch_bounds__(256) void prep_gn_kernel(
    const float* __restrict__ qkvw, const float* __restrict__ qkvb,
    const float* __restrict__ projw,
    short* __restrict__ Wq, short* __restrict__ Wp, float* __restrict__ bias2,
    const float* __restrict__ x, const float* __restrict__ gw,
    const float* __restrict__ gb, short* __restrict__ hT) {
  __shared__ float red[8];
  __shared__ short tile[16 * 1032];
  int tid = threadIdx.x;
  if (blockIdx.x >= 256) {
    int idx = (blockIdx.x - 256) * 256 + tid;
    if (idx < 1536 * 512) {
      int r = idx >> 9, c = idx & 511;
      int sec = r >> 9;            // 0=q, 1=k, 2=v
      int rr = r & 511;
      int nh = rr >> 6, cc = rr & 63;
      int o = nh * 192 + sec * 64 + cc;
      Wq[idx] = f2bf(qkvw[o * 512 + c]);
      if (c == 0) bias2[r] = qkvb[o];
    } else {
      int j = idx - 1536 * 512;
      if (j < 512 * 512) Wp[j] = f2bf(projw[j]);
    }
    return;
  }
  int b = blockIdx.x >> 5, g = blockIdx.x & 31;
  const float* xg = x + (b * 512 + g * 16) * 1024;
  float s = 0.f, ss = 0.f;
#pragma unroll
  for (int r = 0; r < 16; ++r) {
    float4 v = *(const float4*)(xg + r * 1024 + tid * 4);
    s += v.x + v.y + v.z + v.w;
    ss += v.x * v.x + v.y * v.y + v.z * v.z + v.w * v.w;
  }
#pragma unroll
  for (int off = 32; off > 0; off >>= 1) {
    s += __shfl_xor(s, off, 64);
    ss += __shfl_xor(ss, off, 64);
  }
  if ((tid & 63) == 0) { red[tid >> 6] = s; red[4 + (tid >> 6)] = ss; }
  __syncthreads();
  float S = red[0] + red[1] + red[2] + red[3];
  float SS = red[4] + red[5] + red[6] + red[7];
  float mean = S * (1.f / 16384.f);
  float var = SS * (1.f / 16384.f) - mean * mean;
  float inv = rsqrtf(var + 1e-5f);
#pragma unroll
  for (int r = 0; r < 16; ++r) {
    int c = g * 16 + r;
    float a = inv * gw[c];
    float bb = gb[c] - mean * a;
    float4 v = *(const float4*)(xg + r * 1024 + tid * 4);
    short* tr = tile + r * 1032 + tid * 4;
    tr[0] = f2bf(fmaf(v.x, a, bb));
    tr[1] = f2bf(fmaf(v.y, a, bb));
    tr[2] = f2bf(fmaf(v.z, a, bb));
    tr[3] = f2bf(fmaf(v.w, a, bb));
  }
  __syncthreads();
  int r = tid & 15, tq = tid >> 4;
  int c = g * 16 + r;
  short* dst = hT + b * 1024 * 512 + c;
  const short* src = tile + r * 1032;
#pragma unroll
  for (int i = 0; i < 64; ++i) {
    int t = i * 16 + tq;
    dst[t * 512] = src[t];
  }
}

// -------- shared GEMM core v2: K=512, 128x128 tile, BK=64, XOR-swizzled ------
// A,B: [.][512] rows k-contiguous. 8 K-iterations, 16 MFMA per barrier (2x
// the BK=32 ratio). LDS tiles 128x64 stored row-major (128B rows); the 16B
// chunk column is XOR-swizzled with (row&7) on the GLOBAL source address
// (same cache line -> coalescing unchanged; global_load_lds dst stays
// lane-contiguous). Frag reads undo the swizzle -> conflict-free b128.
__device__ __forceinline__ void gemm_k512_b64(
    const short* __restrict__ Ag, const short* __restrict__ Bg,
    short* lA, short* lB, int wid, int lane, v4f acc[4][4]) {
  int wr = (wid >> 1) * 64, wc = (wid & 1) * 64;
  int c16 = lane & 15, q = lane >> 4;
  int srow = lane >> 3;                       // 0..7 within an 8-row slab
  int sw = ((lane & 7) ^ srow) * 8;           // swizzled 16B-chunk (shorts)
  const short* gaw = Ag + (wid * 32 + srow) * 512 + sw;
  const short* gbw = Bg + (wid * 32 + srow) * 512 + sw;
  short* lAw = lA + wid * 2048;               // rows 32*wid.., 64 shorts/row
  short* lBw = lB + wid * 2048;
  int pc0 = (q ^ (c16 & 7)) * 8;              // kstep 0 chunk
  int pc1 = ((4 + q) ^ (c16 & 7)) * 8;        // kstep 1 chunk
  for (int kt = 0; kt < 8; ++kt) {
    int k0 = kt * 64;
#pragma unroll
    for (int t = 0; t < 4; ++t)
      gload16(gaw + t * 8 * 512 + k0, lAw + t * 512);
#pragma unroll
    for (int t = 0; t < 4; ++t)
      gload16(gbw + t * 8 * 512 + k0, lBw + t * 512);
    __syncthreads();
#pragma unroll
    for (int ks = 0; ks < 2; ++ks) {
      int pc = ks ? pc1 : pc0;
      v8s af[4], bf[4];
#pragma unroll
      for (int i = 0; i < 4; ++i)
        af[i] = *(const v8s*)(lA + (wr + i * 16 + c16) * 64 + pc);
#pragma unroll
      for (int j = 0; j < 4; ++j)
        bf[j] = *(const v8s*)(lB + (wc + j * 16 + c16) * 64 + pc);
#pragma unroll
      for (int i = 0; i < 4; ++i)
#pragma unroll
        for (int j = 0; j < 4; ++j)
          acc[i][j] = MFMA(af[i], bf[j], acc[i][j]);
    }
    __syncthreads();
  }
}

// ---------------- QKV GEMM: M=n(8192), N=o(1536) ----------------
// Q pre-scaled by 0.125*log2(e) so attention can use raw v_exp_f32 (2^x).
__global__ __launch_bounds__(256) void qkv_gemm_kernel(
    const short* __restrict__ hT, const short* __restrict__ Wq,
    const float* __restrict__ bias2,
    short* __restrict__ Qb, short* __restrict__ Kb, short* __restrict__ Vb) {
  __shared__ __align__(16) short smem[17408];  // staging 2x8192 / vt 17408 union
  short* lA = smem;
  short* lB = smem + 8192;
  short* vt = smem;
  int bm = blockIdx.x & 63, bo = blockIdx.x >> 6;
  int tid = threadIdx.x, wid = tid >> 6, lane = tid & 63;
  int wr = (wid >> 1) * 64, wc = (wid & 1) * 64;
  int q = lane >> 4, c16 = lane & 15;
  v4f acc[4][4];
#pragma unroll
  for (int i = 0; i < 4; ++i)
#pragma unroll
    for (int j = 0; j < 4; ++j) acc[i][j] = (v4f){0.f, 0.f, 0.f, 0.f};
  gemm_k512_b64(hT + bm * 128 * 512, Wq + bo * 128 * 512, lA, lB, wid, lane, acc);
  float bv[4];
#pragma unroll
  for (int j = 0; j < 4; ++j) bv[j] = bias2[bo * 128 + wc + j * 16 + c16];
  if (bo < 8) {
    short* dst = (bo < 4) ? Qb : Kb;
    float sc = (bo < 4) ? 0.18033688f : 1.f;  // 0.125 * log2(e) folded into Q
    int obase = (bo & 3) * 128 + wc;
#pragma unroll
    for (int j = 0; j < 4; ++j) {
      int ocol = obase + j * 16 + c16;
      int nh = ocol >> 6, cc = ocol & 63;
#pragma unroll
      for (int i = 0; i < 4; ++i)
#pragma unroll
        for (int rr = 0; rr < 4; ++rr) {
          int n = bm * 128 + wr + i * 16 + q * 4 + rr;
          int b_ = n >> 10, t = n & 1023;
          float v = (acc[i][j][rr] + bv[j]) * sc;
          dst[b_ * 524288 + nh * 65536 + t * 64 + cc] = f2bf(v);
        }
    }
  } else {
#pragma unroll
    for (int j = 0; j < 4; ++j) {
      int ol = wc + j * 16 + c16;
#pragma unroll
      for (int i = 0; i < 4; ++i)
#pragma unroll
        for (int rr = 0; rr < 4; ++rr) {
          int nl = wr + i * 16 + q * 4 + rr;
          vt[ol * 136 + nl] = f2bf(acc[i][j][rr] + bv[j]);
        }
    }
    __syncthreads();
    int ol = tid >> 1, hf = tid & 1;
    int ovg = (bo - 8) * 128 + ol;
    const short* src = vt + ol * 136 + hf * 64;
    short* dstv = Vb + ovg * 8192 + bm * 128 + hf * 64;
#pragma unroll
    for (int m = 0; m < 8; ++m)
      *(v8s*)(dstv + m * 8) = *(const v8s*)(src + m * 8);
  }
}

// ---------------- fused attention v8: LDS-staged K/V (unchanged from R8) ----
__global__ __launch_bounds__(512, 4) void attn_kernel(
    const short* __restrict__ Qb, const short* __restrict__ Kb,
    const short* __restrict__ Vb, short* __restrict__ aT) {
  __shared__ __align__(16) short lds[35840];  // K 16K + V 16K + P 38.9K
  int hb = blockIdx.x >> 3, tt = blockIdx.x & 7;
  int b = hb >> 3, nh = hb & 7;
  int tid = threadIdx.x, wid = tid >> 6, lane = tid & 63;
  int chunk = wid >> 2, w4 = wid & 3;
  int q = lane >> 4, c16 = lane & 15;
  const short* Qh = Qb + hb * 65536;
  const short* Kh = Kb + hb * 65536;
  const short* Vh = Vb + nh * 64 * 8192 + b * 1024;
  int t0 = tt * 128 + w4 * 32;
  int sbase = chunk * 512;
  short* Kst = lds + chunk * 4096;
  short* Vst = lds + 8192 + chunk * 4096;
  short* pw = lds + 16384 + wid * 2432;  // wave-private P, stride 76
  v8s qf[2][2];
#pragma unroll
  for (int i = 0; i < 2; ++i)
#pragma unroll
    for (int kk = 0; kk < 2; ++kk)
      qf[i][kk] = *(const v8s*)(Qh + (t0 + i * 16 + c16) * 64 + kk * 32 + q * 8);
  v4f of[2][4];
  float lsum[2] = {0.f, 0.f};
#pragma unroll
  for (int i = 0; i < 2; ++i)
#pragma unroll
    for (int j = 0; j < 4; ++j) of[i][j] = (v4f){0.f, 0.f, 0.f, 0.f};
  int sidx0 = w4 * 128 + lane;
  int sidx1 = w4 * 128 + 64 + lane;
  int r0 = sidx0 >> 3, m0 = (sidx0 & 7) ^ (r0 & 7);
  int r1 = sidx1 >> 3, m1 = (sidx1 & 7) ^ (r1 & 7);
#pragma unroll 1
  for (int st = 0; st < 8; ++st) {
    int s0 = sbase + st * 64;
    gload16(Kh + (s0 + r0) * 64 + m0 * 8, Kst + (w4 * 128) * 8);
    gload16(Kh + (s0 + r1) * 64 + m1 * 8, Kst + (w4 * 128 + 64) * 8);
    gload16(Vh + r0 * 8192 + s0 + m0 * 8, Vst + (w4 * 128) * 8);
    gload16(Vh + r1 * 8192 + s0 + m1 * 8, Vst + (w4 * 128 + 64) * 8);
    __syncthreads();
    v8s kf[4][2];
#pragma unroll
    for (int j = 0; j < 4; ++j) {
      int row = j * 16 + c16;
#pragma unroll
      for (int kk = 0; kk < 2; ++kk) {
        int pc = (kk * 4 + q) ^ (c16 & 7);
        kf[j][kk] = *(const v8s*)(Kst + row * 64 + pc * 8);
      }
    }
#pragma unroll
    for (int j = 0; j < 4; ++j) {
      v4f s0v = (v4f){0.f, 0.f, 0.f, 0.f};
      s0v = MFMA(kf[j][0], qf[0][0], s0v);
      s0v = MFMA(kf[j][1], qf[0][1], s0v);
      v4f s1v = (v4f){0.f, 0.f, 0.f, 0.f};
      s1v = MFMA(kf[j][0], qf[1][0], s1v);
      s1v = MFMA(kf[j][1], qf[1][1], s1v);
      float p00 = __builtin_amdgcn_exp2f(s0v[0]);
      float p01 = __builtin_amdgcn_exp2f(s0v[1]);
      float p02 = __builtin_amdgcn_exp2f(s0v[2]);
      float p03 = __builtin_amdgcn_exp2f(s0v[3]);
      lsum[0] += (p00 + p01) + (p02 + p03);
      uint2 pk0;
      pk0.x = pack2(p00, p01);
      pk0.y = pack2(p02, p03);
      *(uint2*)(pw + c16 * 76 + j * 16 + q * 4) = pk0;
      float p10 = __builtin_amdgcn_exp2f(s1v[0]);
      float p11 = __builtin_amdgcn_exp2f(s1v[1]);
      float p12 = __builtin_amdgcn_exp2f(s1v[2]);
      float p13 = __builtin_amdgcn_exp2f(s1v[3]);
      lsum[1] += (p10 + p11) + (p12 + p13);
      uint2 pk1;
      pk1.x = pack2(p10, p11);
      pk1.y = pack2(p12, p13);
      *(uint2*)(pw + (16 + c16) * 76 + j * 16 + q * 4) = pk1;
    }
    v8s vf[4][2];
#pragma unroll
    for (int j = 0; j < 4; ++j) {
      int row = j * 16 + c16;
#pragma unroll
      for (int kk = 0; kk < 2; ++kk) {
        int pc = (kk * 4 + q) ^ (c16 & 7);
        vf[j][kk] = *(const v8s*)(Vst + row * 64 + pc * 8);
      }
    }
    asm volatile("s_waitcnt lgkmcnt(0)" ::: "memory");
    v8s pa[2][2];
#pragma unroll
    for (int i = 0; i < 2; ++i)
#pragma unroll
      for (int kk = 0; kk < 2; ++kk)
        pa[i][kk] = *(const v8s*)(pw + (i * 16 + c16) * 76 + kk * 32 + q * 8);
#pragma unroll
    for (int i = 0; i < 2; ++i)
#pragma unroll
      for (int j = 0; j < 4; ++j) {
        of[i][j] = MFMA(pa[i][0], vf[j][0], of[i][j]);
        of[i][j] = MFMA(pa[i][1], vf[j][1], of[i][j]);
      }
    __syncthreads();
  }
#pragma unroll
  for (int i = 0; i < 2; ++i) {
    lsum[i] += __shfl_xor(lsum[i], 16, 64);
    lsum[i] += __shfl_xor(lsum[i], 32, 64);
  }
  float* ex = (float*)(lds + 16384) + w4 * 2144;
  __syncthreads();
  if (chunk == 1) {
#pragma unroll
    for (int i = 0; i < 2; ++i) {
#pragma unroll
      for (int j = 0; j < 4; ++j)
#pragma unroll
        for (int rr = 0; rr < 4; ++rr)
          ex[(i * 16 + q * 4 + rr) * 66 + j * 16 + c16] = of[i][j][rr];
      if (q == 0) ex[2112 + i * 16 + c16] = lsum[i];
    }
  }
  __syncthreads();
  if (chunk == 0) {
    short* base = aT + b * 1024 * 512 + nh * 64;
#pragma unroll
    for (int i = 0; i < 2; ++i)
#pragma unroll
      for (int rr = 0; rr < 4; ++rr) {
        int row = i * 16 + q * 4 + rr;
        float inv = 1.f / (__shfl(lsum[i], q * 4 + rr, 64) + ex[2112 + row]);
        int t = t0 + row;
#pragma unroll
        for (int j = 0; j < 4; ++j) {
          float v = (of[i][j][rr] + ex[row * 66 + j * 16 + c16]) * inv;
          base[t * 512 + j * 16 + c16] = f2bf(v);
        }
      }
  }
}

// ---------------- proj GEMM: M=o(512), N=n(8192), fused bias+residual ----------------
__global__ __launch_bounds__(256) void proj_gemm_kernel(
    const short* __restrict__ Wp, const short* __restrict__ aT,
    const float* __restrict__ pbias, const float* __restrict__ x,
    float* __restrict__ out) {
  __shared__ __align__(16) short smem[16384];  // 2 x 128x64 staging (32 KB)
  short* lA = smem;
  short* lB = smem + 8192;
  int bm = blockIdx.x & 3, bn = blockIdx.x >> 2;
  int tid = threadIdx.x, wid = tid >> 6, lane = tid & 63;
  int wr = (wid >> 1) * 64, wc = (wid & 1) * 64;
  int q = lane >> 4, c16 = lane & 15;
  v4f acc[4][4];
#pragma unroll
  for (int i = 0; i < 4; ++i)
#pragma unroll
    for (int j = 0; j < 4; ++j) acc[i][j] = (v4f){0.f, 0.f, 0.f, 0.f};
  gemm_k512_b64(Wp + bm * 128 * 512, aT + bn * 128 * 512, lA, lB, wid, lane, acc);
  int colOff[4];
#pragma unroll
  for (int j = 0; j < 4; ++j) {
    int n = bn * 128 + wc + j * 16 + c16;
    colOff[j] = (n >> 10) * 524288 + (n & 1023);
  }
#pragma unroll
  for (int i = 0; i < 4; ++i)
#pragma unroll
    for (int rr = 0; rr < 4; ++rr) {
      int o = bm * 128 + wr + i * 16 + q * 4 + rr;
      float bs = pbias[o];
      int ro = o * 1024;
#pragma unroll
      for (int j = 0; j < 4; ++j) {
        int a = colOff[j] + ro;
        out[a] = acc[i][j][rr] + bs + x[a];
      }
    }
}

extern "C" void kernel_launch(void* const* d_in, const int* in_sizes, int n_in,
                              void* d_out, int out_size, void* d_ws, size_t ws_size,
                              hipStream_t stream) {
  const float* x = (const float*)d_in[0];
  const float* nw = (const float*)d_in[1];
  const float* nb = (const float*)d_in[2];
  const float* qkvw = (const float*)d_in[3];
  const float* qkvb = (const float*)d_in[4];
  const float* projw = (const float*)d_in[5];
  const float* projb = (const float*)d_in[6];
  float* out = (float*)d_out;
  char* w = (char*)d_ws;
  short* hT = (short*)(w);
  short* aT = (short*)(w + 8388608);
  short* Qb = (short*)(w + 16777216);
  short* Kb = (short*)(w + 25165824);
  short* Vb = (short*)(w + 33554432);
  short* Wq2 = (short*)(w + 41943040);
  short* Wp2 = (short*)(w + 43515904);
  float* b2 = (float*)(w + 44040192);

  hipLaunchKernelGGL(prep_gn_kernel, dim3(4352), dim3(256), 0, stream,
                     qkvw, qkvb, projw, Wq2, Wp2, b2, x, nw, nb, hT);
  hipLaunchKernelGGL(qkv_gemm_kernel, dim3(768), dim3(256), 0, stream,
                     hT, Wq2, b2, Qb, Kb, Vb);
  hipLaunchKernelGGL(attn_kernel, dim3(512), dim3(512), 0, stream, Qb, Kb, Vb, aT);
  hipLaunchKernelGGL(proj_gemm_kernel, dim3(256), dim3(256), 0, stream,
                     Wp2, aT, projb, x, out);
}